// Round 6
// baseline (165.485 us; speedup 1.0000x reference)
//
#include <hip/hip_runtime.h>
#include <math.h>

// B=8, C=128, N=4096, d=16, groups=32
// R22 = gnprep+qkv VERBATIM + attn split-j two-pass.
//   R21 post-mortem: VGPR=128 (predicted 190-240) -> compiler clamped and
//   sank loads; depth-2 collapsed; 67us. All 4 structures (R16/R17/R20/R21)
//   = 63-71us at Occ 18% (2 waves/SIMD, GRID-limited: 512 blk x 4 waves).
//   Per-SIMD per tile: ~540cy issue vs ~2500cy wall -> concurrency-starved;
//   compiler blocks deeper per-wave pipelines (m131-m141 pattern).
//   Fix: split KV loop across blocks. Pass1: grid 1024 (8b x 2jh x 64it),
//   R17 body VERBATIM over 32 tiles, writes unnormalized O-partial f32 +
//   l to ws (XCD-pinned -> 4MB/XCD, L2-resident). Pass2 combine: 512 blks,
//   sums halves, normalizes, oT->LDS, proj+residual epilogue verbatim.
//   Waves/SIMD 2 -> 4, total K/V L2 traffic unchanged.
//   Predict: pass1 30-40us Occ 33-40% VGPR~115; combine 8-14us; total ~135.
//   Pre-commit: pass1 >=50us AT occupancy ~36% => concurrency not limiter.

typedef short v8s __attribute__((ext_vector_type(8)));   // 8 bf16 = 4 VGPRs
typedef float v16f __attribute__((ext_vector_type(16))); // 32x32 acc

__device__ __forceinline__ unsigned short f2bf_rne(float f) {
  unsigned u = __float_as_uint(f);
  u += 0x7fffu + ((u >> 16) & 1u);
  return (unsigned short)(u >> 16);
}

__device__ __forceinline__ v8s mk8(unsigned a, unsigned b, unsigned c, unsigned d) {
  union { unsigned u[4]; v8s s; } x;
  x.u[0] = a; x.u[1] = b; x.u[2] = c; x.u[3] = d;
  return x.s;
}

// pack two fp32 -> dword of 2 bf16 (truncation) in ONE v_perm_b32
__device__ __forceinline__ unsigned pack_trunc(float hi, float lo) {
  return __builtin_amdgcn_perm(__float_as_uint(hi), __float_as_uint(lo), 0x07060302u);
}

// tiled V element index: [b][j>>4][c][j&15]
#define VT(b, n, c) (((((size_t)(b) * 256 + ((n) >> 4)) << 7) + (c)) * 16 + ((n) & 15))

// ws byte offsets
#define WSB_MURS   0u
#define WSB_WCATB  4096u       // 160*128 bf16 = 40960
#define WSB_BCAT   49152u      // 160 f32
#define WSB_PWB    65536u      // 128*128 bf16 = 32768
#define WSB_QBF    131072u     // Q^T [B,16,N] bf16 = 1 MB
#define WSB_KBF    1310720u    // K [B,N,16] bf16 = 1 MB
#define WSB_VBF    2621440u    // 8 MB (tiled)
#define WSB_OPART  11010048u   // O partials f32: 1024 blk * 64 row * 128 = 32 MB
#define WSB_LPART  44564480u   // l partials f32: 1024 blk * 64 = 256 KB

// ---------------------------------------------------------------------------
// gn_stats + prep fused. Grid 256 x 512 thr.  (VERBATIM)
// ---------------------------------------------------------------------------
__global__ __launch_bounds__(512)
void gnprep_kernel(const float* __restrict__ x, float* __restrict__ mu_rs,
                   const float* __restrict__ qw, const float* __restrict__ qb,
                   const float* __restrict__ kw, const float* __restrict__ kb,
                   const float* __restrict__ vw, const float* __restrict__ vb,
                   const float* __restrict__ pw,
                   unsigned short* __restrict__ wcatb, float* __restrict__ bcat,
                   unsigned short* __restrict__ pwb) {
  const int id = blockIdx.x;
  {
    const float qs = 0.36067376022224085f;  // 0.25 * log2(e)
    int idx = id * 512 + threadIdx.x;
    if (idx < 160 * 128) {
      int o = idx >> 7, c = idx & 127;
      float val;
      if (o < 16)       val = qw[o * 128 + c] * qs;
      else if (o < 32)  val = kw[(o - 16) * 128 + c];
      else              val = vw[(o - 32) * 128 + c];
      wcatb[idx] = f2bf_rne(val);
    } else if (idx < 160 * 128 + 160) {
      int o = idx - 160 * 128;
      bcat[o] = (o < 16) ? qb[o] * qs : (o < 32) ? kb[o - 16] : vb[o - 32];
    } else if (idx < 160 * 128 + 160 + 128 * 128) {
      int j = idx - (160 * 128 + 160);
      pwb[j] = f2bf_rne(pw[j]);
    }
  }
  const int bg = (id & 7) * 32 + (id >> 3);   // XCD swizzle: batch = id & 7
  const float4* xp = (const float4*)(x + (size_t)bg * 16384);
  float s = 0.f, ss = 0.f;
#pragma unroll
  for (int u = 0; u < 8; ++u) {
    int i = threadIdx.x + u * 512;
    float4 v = xp[i];
    s  += v.x + v.y + v.z + v.w;
    ss += v.x * v.x + v.y * v.y + v.z * v.z + v.w * v.w;
  }
  for (int off = 32; off > 0; off >>= 1) {
    s  += __shfl_down(s, off, 64);
    ss += __shfl_down(ss, off, 64);
  }
  __shared__ float red[16];
  int lane = threadIdx.x & 63, wid = threadIdx.x >> 6;
  if (lane == 0) { red[wid * 2] = s; red[wid * 2 + 1] = ss; }
  __syncthreads();
  if (threadIdx.x == 0) {
    float S = 0.f, SS = 0.f;
    for (int w = 0; w < 8; ++w) { S += red[w * 2]; SS += red[w * 2 + 1]; }
    float mu  = S * (1.0f / 16384.0f);
    float var = SS * (1.0f / 16384.0f) - mu * mu;
    float rs  = rsqrtf(var + 1e-5f);
    mu_rs[bg * 2]     = mu;
    mu_rs[bg * 2 + 1] = rs;
  }
}

// ---------------------------------------------------------------------------
// QKV: LDS-staged GEMM.  (VERBATIM)
// ---------------------------------------------------------------------------
#define HS 136   // shorts per hs row (128 data + 8 pad); 16B-aligned rows

__global__ __launch_bounds__(512)
void qkv_kernel(const float* __restrict__ x, const float* __restrict__ gnw,
                const float* __restrict__ gnb, const float* __restrict__ mu_rs,
                const unsigned short* __restrict__ wcatb, const float* __restrict__ bcat,
                unsigned short* __restrict__ qTb, unsigned short* __restrict__ kbf,
                unsigned short* __restrict__ vbf) {
  __shared__ alignas(16) unsigned short hs[64 * HS];   // 17408 B
  __shared__ float scsh[128], shsh[128], bsh[160];
  const int id = blockIdx.x;
  const int b = id & 7, nb = (id >> 3) << 6;   // XCD-pinned batch
  const int t = threadIdx.x;
  const int w = t >> 6, lane = t & 63, h = lane >> 5, l = lane & 31;
  const int nsub = w & 1, og = w >> 1;

  if (t < 128) {
    float mu = mu_rs[(b * 32 + (t >> 2)) * 2];
    float rs = mu_rs[(b * 32 + (t >> 2)) * 2 + 1];
    float gw = gnw[t], gb = gnb[t];
    scsh[t] = rs * gw; shsh[t] = gb - mu * rs * gw;
  }
  if (t < 160) bsh[t] = bcat[t];
  __syncthreads();

  // ---- stage: thread = (sn = t&63, c-quad base c00 = (t>>6)*4), 4 iters ----
  const int sn = t & 63;
  const int c00 = (t >> 6) * 4;
  const float* xb = x + ((size_t)b * 128 << 12) + nb + sn;
#pragma unroll
  for (int it = 0; it < 4; ++it) {
    const int c0 = c00 + it * 32;    // wave-uniform
    float f0 = xb[(size_t)(c0)     << 12] * scsh[c0]     + shsh[c0];
    float f1 = xb[(size_t)(c0 + 1) << 12] * scsh[c0 + 1] + shsh[c0 + 1];
    float f2 = xb[(size_t)(c0 + 2) << 12] * scsh[c0 + 2] + shsh[c0 + 2];
    float f3 = xb[(size_t)(c0 + 3) << 12] * scsh[c0 + 3] + shsh[c0 + 3];
    uint2 u;
    u.x = (unsigned)f2bf_rne(f0) | ((unsigned)f2bf_rne(f1) << 16);
    u.y = (unsigned)f2bf_rne(f2) | ((unsigned)f2bf_rne(f3) << 16);
    *(uint2*)(&hs[sn * HS + c0]) = u;
  }
  __syncthreads();

  // ---- MFMA: wave (nsub, og); og0 -> ot{0,1}, og1..3 -> ot{2..4} ----
  const int n = nb + nsub * 32 + l;
  const int otbase = (og == 0) ? 0 : og + 1;
  v16f acc[2];
#pragma unroll
  for (int a2 = 0; a2 < 2; ++a2)
#pragma unroll
    for (int r = 0; r < 16; ++r) acc[a2][r] = 0.f;

#pragma unroll
  for (int ks = 0; ks < 8; ++ks) {
    v8s bf = *(const v8s*)(&hs[(nsub * 32 + l) * HS + ks * 16 + 8 * h]);
    {
      v8s af = *(const v8s*)(wcatb + (otbase * 32 + l) * 128 + ks * 16 + 8 * h);
      acc[0] = __builtin_amdgcn_mfma_f32_32x32x16_bf16(af, bf, acc[0], 0, 0, 0);
    }
    if (og == 0) {
      v8s af = *(const v8s*)(wcatb + (32 + l) * 128 + ks * 16 + 8 * h);
      acc[1] = __builtin_amdgcn_mfma_f32_32x32x16_bf16(af, bf, acc[1], 0, 0, 0);
    }
  }

  // ---- epilogue (unchanged) ----
  if (og == 0) {
    const size_t nqk = ((size_t)b * 4096 + n) << 4;
#pragma unroll
    for (int r = 0; r < 16; ++r) {
      int o = 4 * h + (r & 3) + 8 * (r >> 2);
      unsigned short bv = f2bf_rne(acc[0][r] + bsh[o]);
      if (o < 16) qTb[((size_t)(b * 16 + o) << 12) + n] = bv;
      else        kbf[nqk + o - 16] = bv;
    }
#pragma unroll
    for (int r = 0; r < 16; ++r) {
      int o = 32 + 4 * h + (r & 3) + 8 * (r >> 2);
      vbf[VT(b, n, o - 32)] = f2bf_rne(acc[1][r] + bsh[o]);
    }
  } else {
#pragma unroll
    for (int r = 0; r < 16; ++r) {
      int o = otbase * 32 + 4 * h + (r & 3) + 8 * (r >> 2);
      vbf[VT(b, n, o - 32)] = f2bf_rne(acc[0][r] + bsh[o]);
    }
  }
}

// ---------------------------------------------------------------------------
// R22 pass 1: split-j flash attention. Grid 1024 x 256 thr.
// id: b = id&7 (XCD pin), jh = (id>>3)&1 (KV half), it = id>>4 (i-tile).
// Body = R17 verbatim (depth-1 reg prefetch, barrier-free), 32 tiles.
// Output: unnormalized O-partial f32 [blk][64 rows][128 ch] + l[64].
// ---------------------------------------------------------------------------
__global__ __launch_bounds__(256)
void attn_kernel(const unsigned short* __restrict__ qTb,
                 const unsigned short* __restrict__ kbf,
                 const unsigned short* __restrict__ vbf,
                 float* __restrict__ opart, float* __restrict__ lpart) {
  __shared__ alignas(16) float ovs[9216];   // jsub-combine overlay (36 KB)
  __shared__ float l_lds[64];

  const int id = blockIdx.x;
  const int b = id & 7, jh = (id >> 3) & 1, it = id >> 4;
  const int i0 = it << 6;
  const int t = threadIdx.x;
  const int w = t >> 6, lane = t & 63, h = lane >> 5, l = lane & 31;
  const int jsub = w & 1, ihalf = w >> 1;

  // per-lane base pointers (fragment-coalesced: lane(h,l) at byte l*32+h*16)
  const unsigned short* kg = kbf + ((size_t)b << 16) + jsub * 512 + l * 16 + 8 * h;
  const unsigned short* vg = vbf + ((size_t)b << 19) + jsub * 4096 + l * 16 + 8 * h;

  if (t < 64) l_lds[t] = 0.f;

  // Q B-frag from Q^T [B,16,N]: 8 coalesced b16 loads, once per kernel
  const int iglob = i0 + ihalf * 32 + l;
  unsigned qd[4];
#pragma unroll
  for (int e = 0; e < 4; ++e) {
    unsigned lo = qTb[((size_t)(b * 16 + 8 * h + 2 * e) << 12) + iglob];
    unsigned hi = qTb[((size_t)(b * 16 + 8 * h + 2 * e + 1) << 12) + iglob];
    qd[e] = lo | (hi << 16);
  }
  const v8s qf = mk8(qd[0], qd[1], qd[2], qd[3]);

  v16f zc;
#pragma unroll
  for (int r = 0; r < 16; ++r) zc[r] = 0.f;
  v16f acc[4];
#pragma unroll
  for (int ct = 0; ct < 4; ++ct)
#pragma unroll
    for (int r = 0; r < 16; ++r) acc[ct][r] = 0.f;
  float ls0 = 0.f, ls1 = 0.f, ls2 = 0.f, ls3 = 0.f;

  __syncthreads();   // l_lds zeros visible before any epilogue atomicAdd

  // prologue: own-half tile 0 K frag + 8 V frags into regs
  const int tb = jh << 5;   // first tile of this half
  v8s kf = *(const v8s*)(kg + (size_t)tb * 1024);
  v8s vf[8];
  {
    const unsigned short* vp = vg + (size_t)tb * 8192;
#pragma unroll
    for (int ct = 0; ct < 4; ++ct) {
      vf[2 * ct]     = *(const v8s*)(vp + ct * 512);
      vf[2 * ct + 1] = *(const v8s*)(vp + 2048 + ct * 512);
    }
  }

#pragma unroll 2
  for (int tt = 0; tt < 32; ++tt) {
    const int tn = tb + ((tt + 1) & 31);   // wrap within half: harmless reload

    // issue next-tile loads FIRST; latency hidden under QK + softmax + PV
    v8s kn = *(const v8s*)(kg + (size_t)tn * 1024);
    v8s vn[8];
    const unsigned short* vt = vg + (size_t)tn * 8192;
#pragma unroll
    for (int ct = 0; ct < 4; ++ct) {
      vn[2 * ct]     = *(const v8s*)(vt + ct * 512);
      vn[2 * ct + 1] = *(const v8s*)(vt + 2048 + ct * 512);
    }

    // QK: S^T patch (rows j, cols i) -> P in regs
    v16f st = __builtin_amdgcn_mfma_f32_32x32x16_bf16(kf, qf, zc, 0, 0, 0);
    float pe[16];
#pragma unroll
    for (int r = 0; r < 16; ++r) pe[r] = __builtin_amdgcn_exp2f(st[r]);
    ls0 += pe[0] + pe[4] + pe[8]  + pe[12];
    ls1 += pe[1] + pe[5] + pe[9]  + pe[13];
    ls2 += pe[2] + pe[6] + pe[10] + pe[14];
    ls3 += pe[3] + pe[7] + pe[11] + pe[15];
    unsigned G[8];
#pragma unroll
    for (int g = 0; g < 4; ++g) {
      G[2 * g]     = pack_trunc(pe[4 * g + 1], pe[4 * g]);
      G[2 * g + 1] = pack_trunc(pe[4 * g + 3], pe[4 * g + 2]);
    }
    // half-wave exchange via v_permlane32_swap_b32 (pure VALU; proven)
    unsigned A0 = G[0], B0 = G[2], A1 = G[1], B1 = G[3];
    unsigned A2 = G[4], B2 = G[6], A3 = G[5], B3 = G[7];
    asm("v_permlane32_swap_b32 %0, %1" : "+v"(A0), "+v"(B0));
    asm("v_permlane32_swap_b32 %0, %1" : "+v"(A1), "+v"(B1));
    asm("v_permlane32_swap_b32 %0, %1" : "+v"(A2), "+v"(B2));
    asm("v_permlane32_swap_b32 %0, %1" : "+v"(A3), "+v"(B3));
    v8s pf0 = mk8(A0, A1, B0, B1);
    v8s pf1 = mk8(A2, A3, B2, B3);

    // PV on current-tile register fragments (no LDS, no barrier)
    __builtin_amdgcn_s_setprio(1);
#pragma unroll
    for (int ct = 0; ct < 4; ++ct) {
      acc[ct] = __builtin_amdgcn_mfma_f32_32x32x16_bf16(vf[2 * ct],     pf0, acc[ct], 0, 0, 0);
      acc[ct] = __builtin_amdgcn_mfma_f32_32x32x16_bf16(vf[2 * ct + 1], pf1, acc[ct], 0, 0, 0);
    }
    __builtin_amdgcn_s_setprio(0);

    // rotate prefetch (copies vanish under unroll-2 renaming)
    kf = kn;
#pragma unroll
    for (int u = 0; u < 8; ++u) vf[u] = vn[u];
  }

  // ---- epilogue: jsub combine, write unnormalized partials + l ----
  atomicAdd(&l_lds[ihalf * 32 + l], (ls0 + ls1) + (ls2 + ls3));
  __syncthreads();   // l complete; ovs free

  float* const ov = ovs;
  if (jsub == 1) {
#pragma unroll
    for (int ct = 0; ct < 4; ++ct)
#pragma unroll
      for (int q = 0; q < 4; ++q) {
        float4 v4 = {acc[ct][4 * q], acc[ct][4 * q + 1],
                     acc[ct][4 * q + 2], acc[ct][4 * q + 3]};
        *(float4*)&ov[((ct * 2 + ihalf) * 32 + l) * 36 + 4 * h + 8 * q] = v4;
      }
  }
  __syncthreads();
  float* const opb = opart + ((size_t)id << 13);   // 64 rows * 128 ch
  if (jsub == 0) {
    const int row = ihalf * 32 + l;
#pragma unroll
    for (int ct = 0; ct < 4; ++ct)
#pragma unroll
      for (int q = 0; q < 4; ++q) {
        float4 v4 = *(float4*)&ov[((ct * 2 + ihalf) * 32 + l) * 36 + 4 * h + 8 * q];
        v4.x += acc[ct][4 * q];
        v4.y += acc[ct][4 * q + 1];
        v4.z += acc[ct][4 * q + 2];
        v4.w += acc[ct][4 * q + 3];
        *(float4*)(opb + row * 128 + ct * 32 + 4 * h + 8 * q) = v4;
      }
  }
  if (t < 64) lpart[((size_t)id << 6) + t] = l_lds[t];
}

// ---------------------------------------------------------------------------
// R22 pass 2: combine halves + normalize + fused proj + residual.
// Grid 512 x 256 thr (b = id&7, it = id>>3). Epilogue logic = R17 verbatim.
// ---------------------------------------------------------------------------
#define OTS 136                   // O^T row stride in shorts (68 dwords)

__global__ __launch_bounds__(256)
void combine_kernel(const float* __restrict__ opart, const float* __restrict__ lpart,
                    const unsigned short* __restrict__ pwb,
                    const float* __restrict__ pb,
                    const float* __restrict__ x,
                    float* __restrict__ out) {
  __shared__ alignas(16) unsigned short oT[64 * OTS];   // 17408 B
  __shared__ float pbs[128];

  const int id = blockIdx.x;
  const int b = id & 7, it = id >> 3, i0 = it << 6;
  const int t = threadIdx.x;
  const int w = t >> 6, lane = t & 63, h = lane >> 5, l = lane & 31;

  if (t < 128) pbs[t] = pb[t];

  // pass-1 block ids for the two j-halves of (b, it)
  const int id0 = (it << 4) + b;          // jh=0
  const int id1 = (it << 4) + 8 + b;      // jh=1

  // thread (row = t&63, cg = t>>6) combines 32 channels of one row
  {
    const int row = t & 63, cg = t >> 6;
    const float* p0 = opart + ((size_t)id0 << 13) + row * 128 + cg * 32;
    const float* p1 = opart + ((size_t)id1 << 13) + row * 128 + cg * 32;
    const float li = 1.f / (lpart[((size_t)id0 << 6) + row] +
                            lpart[((size_t)id1 << 6) + row]);
#pragma unroll
    for (int cc = 0; cc < 8; ++cc) {
      float4 a = *(const float4*)(p0 + cc * 4);
      float4 c = *(const float4*)(p1 + cc * 4);
      float s0 = (a.x + c.x) * li, s1 = (a.y + c.y) * li;
      float s2 = (a.z + c.z) * li, s3 = (a.w + c.w) * li;
      uint2 dw;
      dw.x = (unsigned)f2bf_rne(s0) | ((unsigned)f2bf_rne(s1) << 16);
      dw.y = (unsigned)f2bf_rne(s2) | ((unsigned)f2bf_rne(s3) << 16);
      *(uint2*)(&oT[row * OTS + cg * 32 + cc * 4]) = dw;
    }
  }
  __syncthreads();

  // fused proj: wave w -> e-tile w (32 e), both n-subs. out = pw@O + pb + x.
#pragma unroll
  for (int nsub = 0; nsub < 2; ++nsub) {
    v16f a2;
#pragma unroll
    for (int r = 0; r < 16; ++r) a2[r] = 0.f;
#pragma unroll
    for (int ks = 0; ks < 8; ++ks) {
      v8s bf = *(const v8s*)(&oT[(nsub * 32 + l) * OTS + ks * 16 + 8 * h]);
      v8s af = *(const v8s*)(pwb + (w * 32 + l) * 128 + ks * 16 + 8 * h);
      a2 = __builtin_amdgcn_mfma_f32_32x32x16_bf16(af, bf, a2, 0, 0, 0);
    }
    const int n = i0 + nsub * 32 + l;
#pragma unroll
    for (int r = 0; r < 16; ++r) {
      int e = w * 32 + 4 * h + (r & 3) + 8 * (r >> 2);
      size_t idx = ((size_t)(b * 128 + e) << 12) + n;
      out[idx] = a2[r] + pbs[e] + x[idx];
    }
  }
}

// ---------------------------------------------------------------------------
extern "C" void kernel_launch(void* const* d_in, const int* in_sizes, int n_in,
                              void* d_out, int out_size, void* d_ws, size_t ws_size,
                              hipStream_t stream) {
  const float* x   = (const float*)d_in[0];
  const float* gnw = (const float*)d_in[1];
  const float* gnb = (const float*)d_in[2];
  const float* qw  = (const float*)d_in[3];
  const float* qb  = (const float*)d_in[4];
  const float* kw  = (const float*)d_in[5];
  const float* kb  = (const float*)d_in[6];
  const float* vw  = (const float*)d_in[7];
  const float* vb  = (const float*)d_in[8];
  const float* pw  = (const float*)d_in[9];
  const float* pb  = (const float*)d_in[10];
  float* out = (float*)d_out;
  char* ws = (char*)d_ws;

  float* mu_rs = (float*)(ws + WSB_MURS);
  unsigned short* wcatb = (unsigned short*)(ws + WSB_WCATB);
  float* bcat = (float*)(ws + WSB_BCAT);
  unsigned short* pwb = (unsigned short*)(ws + WSB_PWB);
  unsigned short* qTb = (unsigned short*)(ws + WSB_QBF);
  unsigned short* kbf = (unsigned short*)(ws + WSB_KBF);
  unsigned short* vbf = (unsigned short*)(ws + WSB_VBF);
  float* opart = (float*)(ws + WSB_OPART);
  float* lpart = (float*)(ws + WSB_LPART);

  hipLaunchKernelGGL(gnprep_kernel, dim3(256), dim3(512), 0, stream,
                     x, mu_rs, qw, qb, kw, kb, vw, vb, pw, wcatb, bcat, pwb);
  hipLaunchKernelGGL(qkv_kernel, dim3(512), dim3(512), 0, stream,
                     x, gnw, gnb, mu_rs, wcatb, bcat, qTb, kbf, vbf);
  hipLaunchKernelGGL(attn_kernel, dim3(1024), dim3(256), 0, stream,
                     qTb, kbf, vbf, opart, lpart);
  hipLaunchKernelGGL(combine_kernel, dim3(512), dim3(256), 0, stream,
                     opart, lpart, pwb, pb, x, out);
}

// Round 7
// 159.213 us; speedup vs baseline: 1.0394x; 1.0394x over previous
//
#include <hip/hip_runtime.h>
#include <math.h>

// B=8, C=128, N=4096, d=16, groups=32
// R23 = gnprep verbatim + qkv (K/V store layouts changed to fragment-major)
//   + attn: LDS-shared no-dup V/K with T4 counted-vmcnt pipeline.
//   Evidence chain: R17(reg,63) = R21(deep-reg,67) = R22(2x blocks,67) at
//   constant 1 GB L2 traffic -> throughput-bound on L2->CU (~28 B/cy/CU).
//   Only bytes move the needle: stage V(16KB)+K(2KB) ONCE per block per tile
//   (vs 36+4KB duplicated reads) -> 2.3 MB/CU, floor ~32us.
//   R20's two killers fixed:
//   (1) barrier drain -> raw s_barrier + per-wave counted s_waitcnt vmcnt(2c)
//       (c = own chunks/iter: 4 or 5), 4-buffer rotation, stage depth 2.
//       All loop loads are global_load_lds -> exact counting, over-drain-safe.
//   (2) bank conflicts -> NEW fragment-major layouts VT2/K2 (we own the
//       producer): each MFMA fragment's wave-data contiguous; LDS read =
//       base + lane*16 -> 2-way = free (m136). No swizzle.
//   Predict: attn 40-50us (>=58 kills the L2 model), VGPR 80-105, LDS 74.5KB,
//   conflicts <0.3M, WRITE 16.4MB, total ~125-140.

typedef short v8s __attribute__((ext_vector_type(8)));   // 8 bf16 = 4 VGPRs
typedef float v16f __attribute__((ext_vector_type(16))); // 32x32 acc

__device__ __forceinline__ unsigned short f2bf_rne(float f) {
  unsigned u = __float_as_uint(f);
  u += 0x7fffu + ((u >> 16) & 1u);
  return (unsigned short)(u >> 16);
}

__device__ __forceinline__ v8s mk8(unsigned a, unsigned b, unsigned c, unsigned d) {
  union { unsigned u[4]; v8s s; } x;
  x.u[0] = a; x.u[1] = b; x.u[2] = c; x.u[3] = d;
  return x.s;
}

// pack two fp32 -> dword of 2 bf16 (truncation) in ONE v_perm_b32
__device__ __forceinline__ unsigned pack_trunc(float hi, float lo) {
  return __builtin_amdgcn_perm(__float_as_uint(hi), __float_as_uint(lo), 0x07060302u);
}

// async 16B global -> LDS (DMA). LDS dest = uniform base + lane*16 (HW adds).
__device__ __forceinline__ void gl_lds16(const void* g, void* l) {
  __builtin_amdgcn_global_load_lds(
      (const __attribute__((address_space(1))) unsigned int*)g,
      (__attribute__((address_space(3))) unsigned int*)l, 16, 0, 0);
}

// fragment-major V: short index for element (n, c).
// n bits: tile(6)|jsub(1)|half(1)|h(1)|je(3); c bits: ct(2)|l(5).
// tile block 8192 shorts; fragment (jsub*8+half*4+ct) of 512 shorts;
// within fragment: lane (h*32+l) holds 8 shorts at lane*8.
#define VT2(b, n, c) (((size_t)(b) * 64 + ((n) >> 6)) * 8192 + \
   ((((n) >> 5) & 1) * 8 + (((n) >> 4) & 1) * 4 + ((c) >> 5)) * 512 + \
   ((((n) >> 3) & 1) * 32 + ((c) & 31)) * 8 + ((n) & 7))

// fragment-major K: short index for element (n, d), d in 0..15.
// tile block 1024 shorts; fragment jsub of 512; lane (h*32+l) at lane*8.
#define K2(b, n, d) (((size_t)(b) * 64 + ((n) >> 6)) * 1024 + \
   ((((n) >> 5) & 1)) * 512 + (((d) >> 3) * 32 + ((n) & 31)) * 8 + ((d) & 7))

// ws byte offsets
#define WSB_MURS   0u
#define WSB_WCATB  4096u       // 160*128 bf16 = 40960
#define WSB_BCAT   49152u      // 160 f32
#define WSB_PWB    65536u      // 128*128 bf16 = 32768
#define WSB_QBF    131072u     // Q^T [B,16,N] bf16 = 1 MB
#define WSB_KBF    1310720u    // K fragment-major = 1 MB
#define WSB_VBF    2621440u    // 8 MB (fragment-major tiled)

// ---------------------------------------------------------------------------
// gn_stats + prep fused. Grid 256 x 512 thr.  (VERBATIM)
// ---------------------------------------------------------------------------
__global__ __launch_bounds__(512)
void gnprep_kernel(const float* __restrict__ x, float* __restrict__ mu_rs,
                   const float* __restrict__ qw, const float* __restrict__ qb,
                   const float* __restrict__ kw, const float* __restrict__ kb,
                   const float* __restrict__ vw, const float* __restrict__ vb,
                   const float* __restrict__ pw,
                   unsigned short* __restrict__ wcatb, float* __restrict__ bcat,
                   unsigned short* __restrict__ pwb) {
  const int id = blockIdx.x;
  {
    const float qs = 0.36067376022224085f;  // 0.25 * log2(e)
    int idx = id * 512 + threadIdx.x;
    if (idx < 160 * 128) {
      int o = idx >> 7, c = idx & 127;
      float val;
      if (o < 16)       val = qw[o * 128 + c] * qs;
      else if (o < 32)  val = kw[(o - 16) * 128 + c];
      else              val = vw[(o - 32) * 128 + c];
      wcatb[idx] = f2bf_rne(val);
    } else if (idx < 160 * 128 + 160) {
      int o = idx - 160 * 128;
      bcat[o] = (o < 16) ? qb[o] * qs : (o < 32) ? kb[o - 16] : vb[o - 32];
    } else if (idx < 160 * 128 + 160 + 128 * 128) {
      int j = idx - (160 * 128 + 160);
      pwb[j] = f2bf_rne(pw[j]);
    }
  }
  const int bg = (id & 7) * 32 + (id >> 3);   // XCD swizzle: batch = id & 7
  const float4* xp = (const float4*)(x + (size_t)bg * 16384);
  float s = 0.f, ss = 0.f;
#pragma unroll
  for (int u = 0; u < 8; ++u) {
    int i = threadIdx.x + u * 512;
    float4 v = xp[i];
    s  += v.x + v.y + v.z + v.w;
    ss += v.x * v.x + v.y * v.y + v.z * v.z + v.w * v.w;
  }
  for (int off = 32; off > 0; off >>= 1) {
    s  += __shfl_down(s, off, 64);
    ss += __shfl_down(ss, off, 64);
  }
  __shared__ float red[16];
  int lane = threadIdx.x & 63, wid = threadIdx.x >> 6;
  if (lane == 0) { red[wid * 2] = s; red[wid * 2 + 1] = ss; }
  __syncthreads();
  if (threadIdx.x == 0) {
    float S = 0.f, SS = 0.f;
    for (int w = 0; w < 8; ++w) { S += red[w * 2]; SS += red[w * 2 + 1]; }
    float mu  = S * (1.0f / 16384.0f);
    float var = SS * (1.0f / 16384.0f) - mu * mu;
    float rs  = rsqrtf(var + 1e-5f);
    mu_rs[bg * 2]     = mu;
    mu_rs[bg * 2 + 1] = rs;
  }
}

// ---------------------------------------------------------------------------
// QKV: LDS-staged GEMM. (VERBATIM except K/V stores -> K2/VT2 layouts)
// ---------------------------------------------------------------------------
#define HS 136   // shorts per hs row (128 data + 8 pad); 16B-aligned rows

__global__ __launch_bounds__(512)
void qkv_kernel(const float* __restrict__ x, const float* __restrict__ gnw,
                const float* __restrict__ gnb, const float* __restrict__ mu_rs,
                const unsigned short* __restrict__ wcatb, const float* __restrict__ bcat,
                unsigned short* __restrict__ qTb, unsigned short* __restrict__ kbf,
                unsigned short* __restrict__ vbf) {
  __shared__ alignas(16) unsigned short hs[64 * HS];   // 17408 B
  __shared__ float scsh[128], shsh[128], bsh[160];
  const int id = blockIdx.x;
  const int b = id & 7, nb = (id >> 3) << 6;   // XCD-pinned batch
  const int t = threadIdx.x;
  const int w = t >> 6, lane = t & 63, h = lane >> 5, l = lane & 31;
  const int nsub = w & 1, og = w >> 1;

  if (t < 128) {
    float mu = mu_rs[(b * 32 + (t >> 2)) * 2];
    float rs = mu_rs[(b * 32 + (t >> 2)) * 2 + 1];
    float gw = gnw[t], gb = gnb[t];
    scsh[t] = rs * gw; shsh[t] = gb - mu * rs * gw;
  }
  if (t < 160) bsh[t] = bcat[t];
  __syncthreads();

  // ---- stage: thread = (sn = t&63, c-quad base c00 = (t>>6)*4), 4 iters ----
  const int sn = t & 63;
  const int c00 = (t >> 6) * 4;
  const float* xb = x + ((size_t)b * 128 << 12) + nb + sn;
#pragma unroll
  for (int it = 0; it < 4; ++it) {
    const int c0 = c00 + it * 32;    // wave-uniform
    float f0 = xb[(size_t)(c0)     << 12] * scsh[c0]     + shsh[c0];
    float f1 = xb[(size_t)(c0 + 1) << 12] * scsh[c0 + 1] + shsh[c0 + 1];
    float f2 = xb[(size_t)(c0 + 2) << 12] * scsh[c0 + 2] + shsh[c0 + 2];
    float f3 = xb[(size_t)(c0 + 3) << 12] * scsh[c0 + 3] + shsh[c0 + 3];
    uint2 u;
    u.x = (unsigned)f2bf_rne(f0) | ((unsigned)f2bf_rne(f1) << 16);
    u.y = (unsigned)f2bf_rne(f2) | ((unsigned)f2bf_rne(f3) << 16);
    *(uint2*)(&hs[sn * HS + c0]) = u;
  }
  __syncthreads();

  // ---- MFMA: wave (nsub, og); og0 -> ot{0,1}, og1..3 -> ot{2..4} ----
  const int n = nb + nsub * 32 + l;
  const int otbase = (og == 0) ? 0 : og + 1;
  v16f acc[2];
#pragma unroll
  for (int a2 = 0; a2 < 2; ++a2)
#pragma unroll
    for (int r = 0; r < 16; ++r) acc[a2][r] = 0.f;

#pragma unroll
  for (int ks = 0; ks < 8; ++ks) {
    v8s bf = *(const v8s*)(&hs[(nsub * 32 + l) * HS + ks * 16 + 8 * h]);
    {
      v8s af = *(const v8s*)(wcatb + (otbase * 32 + l) * 128 + ks * 16 + 8 * h);
      acc[0] = __builtin_amdgcn_mfma_f32_32x32x16_bf16(af, bf, acc[0], 0, 0, 0);
    }
    if (og == 0) {
      v8s af = *(const v8s*)(wcatb + (32 + l) * 128 + ks * 16 + 8 * h);
      acc[1] = __builtin_amdgcn_mfma_f32_32x32x16_bf16(af, bf, acc[1], 0, 0, 0);
    }
  }

  // ---- epilogue (K/V stores in fragment-major layouts) ----
  if (og == 0) {
#pragma unroll
    for (int r = 0; r < 16; ++r) {
      int o = 4 * h + (r & 3) + 8 * (r >> 2);
      unsigned short bv = f2bf_rne(acc[0][r] + bsh[o]);
      if (o < 16) qTb[((size_t)(b * 16 + o) << 12) + n] = bv;
      else        kbf[K2(b, n, o - 16)] = bv;
    }
#pragma unroll
    for (int r = 0; r < 16; ++r) {
      int o = 32 + 4 * h + (r & 3) + 8 * (r >> 2);
      vbf[VT2(b, n, o - 32)] = f2bf_rne(acc[1][r] + bsh[o]);
    }
  } else {
#pragma unroll
    for (int r = 0; r < 16; ++r) {
      int o = otbase * 32 + 4 * h + (r & 3) + 8 * (r >> 2);
      vbf[VT2(b, n, o - 32)] = f2bf_rne(acc[0][r] + bsh[o]);
    }
  }
}

// ---------------------------------------------------------------------------
// R23 flash attention + fused proj: 4 waves (jsub, ihalf); V+K staged once
// per block per tile via global_load_lds into 4-buffer rotation (18 KB each),
// counted per-wave vmcnt + raw s_barrier (no drain in loop). PV/QK frags =
// contiguous lane*16 ds_read_b128 (conflict-free by layout).
// Grid 512 x 256 thr.
// ---------------------------------------------------------------------------
#define OTS 136                   // O^T row stride in shorts (68 dwords)
#define BUFB 18432                // bytes per tile buffer: V 16K + K 2K

__global__ __launch_bounds__(256)
void attn_kernel(const unsigned short* __restrict__ qTb,
                 const unsigned short* __restrict__ kbf,
                 const unsigned short* __restrict__ vbf,
                 const unsigned short* __restrict__ pwb,
                 const float* __restrict__ pb,
                 const float* __restrict__ x,
                 float* __restrict__ out) {
  // 4 x 18KB tile buffers; epilogue overlays the front as ov / oT
  __shared__ alignas(16) unsigned char smem[4 * BUFB];   // 73728 B
  __shared__ float l_lds[64];
  __shared__ float pbs[128];

  const int id = blockIdx.x;
  const int b = id & 7, i0 = (id >> 3) << 6;   // XCD-pinned batch, 64-i tile
  const int t = threadIdx.x;
  const int w = t >> 6, lane = t & 63, h = lane >> 5, l = lane & 31;
  const int jsub = w & 1, ihalf = w >> 1;

  const char* vgb = (const char*)vbf + ((size_t)b << 20);      // 1 MB/batch
  const char* kgb = (const char*)kbf + ((size_t)b * 131072);   // 128 KB/batch

  if (t < 128) pbs[t] = pb[t];
  if (t < 64) l_lds[t] = 0.f;

  // Q B-frag from Q^T [B,16,N]: 8 coalesced b16 loads, once per kernel
  const int iglob = i0 + ihalf * 32 + l;
  unsigned qd[4];
#pragma unroll
  for (int e = 0; e < 4; ++e) {
    unsigned lo = qTb[((size_t)(b * 16 + 8 * h + 2 * e) << 12) + iglob];
    unsigned hi = qTb[((size_t)(b * 16 + 8 * h + 2 * e + 1) << 12) + iglob];
    qd[e] = lo | (hi << 16);
  }
  const v8s qf = mk8(qd[0], qd[1], qd[2], qd[3]);

  v16f zc;
#pragma unroll
  for (int r = 0; r < 16; ++r) zc[r] = 0.f;
  v16f acc[4];
#pragma unroll
  for (int ct = 0; ct < 4; ++ct)
#pragma unroll
    for (int r = 0; r < 16; ++r) acc[ct][r] = 0.f;
  float ls0 = 0.f, ls1 = 0.f, ls2 = 0.f, ls3 = 0.f;

  // stage tile ts into buffer ts&3; wave w: V chunks qi*4+w, waves 2,3 add K
#define STAGE_T(TS) {                                                      \
    const int ts_ = (TS) & 63;                                             \
    const char* vs_ = vgb + (size_t)ts_ * 16384;                           \
    char* dst_ = (char*)smem + (size_t)(ts_ & 3) * BUFB;                   \
    _Pragma("unroll") for (int qi = 0; qi < 4; ++qi) {                     \
      const int ch = qi * 4 + w;                                           \
      gl_lds16(vs_ + ch * 1024 + lane * 16, dst_ + ch * 1024);             \
    }                                                                      \
    if (w >= 2)                                                            \
      gl_lds16(kgb + (size_t)ts_ * 2048 + (w - 2) * 1024 + lane * 16,      \
               dst_ + 16384 + (w - 2) * 1024);                             \
  }

  // prologue: tiles 0 and 1 in flight (depth 2)
  STAGE_T(0);
  STAGE_T(1);

  for (int tile = 0; tile < 64; ++tile) {
    STAGE_T(tile + 2);   // wrap harmless reload

    // own chunks of tile-t complete (keep the 2 newest stage groups in
    // flight); over-drain-safe counting: all loop vmem is gl_lds.
    if (w >= 2) { asm volatile("s_waitcnt vmcnt(10)" ::: "memory"); }
    else        { asm volatile("s_waitcnt vmcnt(8)"  ::: "memory"); }
    __builtin_amdgcn_sched_barrier(0);
    __builtin_amdgcn_s_barrier();   // raw: no vmcnt(0) drain

    const unsigned short* bufp =
        (const unsigned short*)(smem + (size_t)(tile & 3) * BUFB);

    // QK: K frag from LDS (fragment-major, lane*16 contiguous)
    v8s kf = *(const v8s*)(bufp + 8192 + jsub * 512 + lane * 8);
    v16f st = __builtin_amdgcn_mfma_f32_32x32x16_bf16(kf, qf, zc, 0, 0, 0);
    float pe[16];
#pragma unroll
    for (int r = 0; r < 16; ++r) pe[r] = __builtin_amdgcn_exp2f(st[r]);
    ls0 += pe[0] + pe[4] + pe[8]  + pe[12];
    ls1 += pe[1] + pe[5] + pe[9]  + pe[13];
    ls2 += pe[2] + pe[6] + pe[10] + pe[14];
    ls3 += pe[3] + pe[7] + pe[11] + pe[15];
    unsigned G[8];
#pragma unroll
    for (int g = 0; g < 4; ++g) {
      G[2 * g]     = pack_trunc(pe[4 * g + 1], pe[4 * g]);
      G[2 * g + 1] = pack_trunc(pe[4 * g + 3], pe[4 * g + 2]);
    }
    // half-wave exchange via v_permlane32_swap_b32 (pure VALU; proven)
    unsigned A0 = G[0], B0 = G[2], A1 = G[1], B1 = G[3];
    unsigned A2 = G[4], B2 = G[6], A3 = G[5], B3 = G[7];
    asm("v_permlane32_swap_b32 %0, %1" : "+v"(A0), "+v"(B0));
    asm("v_permlane32_swap_b32 %0, %1" : "+v"(A1), "+v"(B1));
    asm("v_permlane32_swap_b32 %0, %1" : "+v"(A2), "+v"(B2));
    asm("v_permlane32_swap_b32 %0, %1" : "+v"(A3), "+v"(B3));
    v8s pf0 = mk8(A0, A1, B0, B1);
    v8s pf1 = mk8(A2, A3, B2, B3);

    // PV: fragment-major V frags (conflict-free contiguous reads)
    __builtin_amdgcn_s_setprio(1);
#pragma unroll
    for (int ct = 0; ct < 4; ++ct) {
      v8s vf0 = *(const v8s*)(bufp + (jsub * 8 + ct) * 512 + lane * 8);
      v8s vf1 = *(const v8s*)(bufp + (jsub * 8 + 4 + ct) * 512 + lane * 8);
      acc[ct] = __builtin_amdgcn_mfma_f32_32x32x16_bf16(vf0, pf0, acc[ct], 0, 0, 0);
      acc[ct] = __builtin_amdgcn_mfma_f32_32x32x16_bf16(vf1, pf1, acc[ct], 0, 0, 0);
    }
    __builtin_amdgcn_s_setprio(0);
  }

  // ---- epilogue: jsub combine, then fused proj (R17 logic verbatim) ----
  atomicAdd(&l_lds[ihalf * 32 + l], (ls0 + ls1) + (ls2 + ls3));
  __syncthreads();   // full drain (leftover DMA lands) + l complete

  float* const ov = (float*)smem;   // f32 combine overlay
  if (jsub == 1) {
#pragma unroll
    for (int ct = 0; ct < 4; ++ct)
#pragma unroll
      for (int q = 0; q < 4; ++q) {
        float4 v4 = {acc[ct][4 * q], acc[ct][4 * q + 1],
                     acc[ct][4 * q + 2], acc[ct][4 * q + 3]};
        *(float4*)&ov[((ct * 2 + ihalf) * 32 + l) * 36 + 4 * h + 8 * q] = v4;
      }
  }
  __syncthreads();
  if (jsub == 0) {
#pragma unroll
    for (int ct = 0; ct < 4; ++ct)
#pragma unroll
      for (int q = 0; q < 4; ++q) {
        float4 v4 = *(float4*)&ov[((ct * 2 + ihalf) * 32 + l) * 36 + 4 * h + 8 * q];
        acc[ct][4 * q]     += v4.x;
        acc[ct][4 * q + 1] += v4.y;
        acc[ct][4 * q + 2] += v4.z;
        acc[ct][4 * q + 3] += v4.w;
      }
  }
  __syncthreads();   // ov reads complete; smem reusable

  // jsub=0 waves write normalized O^T bf16 [n_local][c], stride OTS
  unsigned short* const oT = (unsigned short*)smem;
  if (jsub == 0) {
    const float li = 1.f / l_lds[ihalf * 32 + l];
    const int nrow = ihalf * 32 + l;
#pragma unroll
    for (int ct = 0; ct < 4; ++ct)
#pragma unroll
      for (int r = 0; r < 16; r += 2) {
        int c = ct * 32 + 4 * h + (r & 3) + 8 * (r >> 2);   // even
        unsigned dw = (unsigned)f2bf_rne(acc[ct][r] * li) |
                      ((unsigned)f2bf_rne(acc[ct][r + 1] * li) << 16);
        *(unsigned*)(&oT[nrow * OTS + c]) = dw;
      }
  }
  __syncthreads();

  // fused proj: wave w -> e-tile w (32 e), both n-subs. out = pw@O + pb + x.
#pragma unroll
  for (int nsub = 0; nsub < 2; ++nsub) {
    v16f a2;
#pragma unroll
    for (int r = 0; r < 16; ++r) a2[r] = 0.f;
#pragma unroll
    for (int ks = 0; ks < 8; ++ks) {
      v8s bf = *(const v8s*)(&oT[(nsub * 32 + l) * OTS + ks * 16 + 8 * h]);
      v8s af = *(const v8s*)(pwb + (w * 32 + l) * 128 + ks * 16 + 8 * h);
      a2 = __builtin_amdgcn_mfma_f32_32x32x16_bf16(af, bf, a2, 0, 0, 0);
    }
    const int n = i0 + nsub * 32 + l;
#pragma unroll
    for (int r = 0; r < 16; ++r) {
      int e = w * 32 + 4 * h + (r & 3) + 8 * (r >> 2);
      size_t idx = ((size_t)(b * 128 + e) << 12) + n;
      out[idx] = a2[r] + pbs[e] + x[idx];
    }
  }
}

// ---------------------------------------------------------------------------
extern "C" void kernel_launch(void* const* d_in, const int* in_sizes, int n_in,
                              void* d_out, int out_size, void* d_ws, size_t ws_size,
                              hipStream_t stream) {
  const float* x   = (const float*)d_in[0];
  const float* gnw = (const float*)d_in[1];
  const float* gnb = (const float*)d_in[2];
  const float* qw  = (const float*)d_in[3];
  const float* qb  = (const float*)d_in[4];
  const float* kw  = (const float*)d_in[5];
  const float* kb  = (const float*)d_in[6];
  const float* vw  = (const float*)d_in[7];
  const float* vb  = (const float*)d_in[8];
  const float* pw  = (const float*)d_in[9];
  const float* pb  = (const float*)d_in[10];
  float* out = (float*)d_out;
  char* ws = (char*)d_ws;

  float* mu_rs = (float*)(ws + WSB_MURS);
  unsigned short* wcatb = (unsigned short*)(ws + WSB_WCATB);
  float* bcat = (float*)(ws + WSB_BCAT);
  unsigned short* pwb = (unsigned short*)(ws + WSB_PWB);
  unsigned short* qTb = (unsigned short*)(ws + WSB_QBF);
  unsigned short* kbf = (unsigned short*)(ws + WSB_KBF);
  unsigned short* vbf = (unsigned short*)(ws + WSB_VBF);

  hipLaunchKernelGGL(gnprep_kernel, dim3(256), dim3(512), 0, stream,
                     x, mu_rs, qw, qb, kw, kb, vw, vb, pw, wcatb, bcat, pwb);
  hipLaunchKernelGGL(qkv_kernel, dim3(512), dim3(512), 0, stream,
                     x, gnw, gnb, mu_rs, wcatb, bcat, qTb, kbf, vbf);
  hipLaunchKernelGGL(attn_kernel, dim3(512), dim3(256), 0, stream,
                     qTb, kbf, vbf, pwb, pb, x, out);
}